// Round 1
// baseline (248.420 us; speedup 1.0000x reference)
//
#include <hip/hip_runtime.h>

#define IX 1440
#define IY 720
#define NB 4
#define NCH 12
#define PLANE (IY * IX)            // 1,036,800
#define NOUT (NB * NCH * PLANE)    // 49,766,400

__global__ void zero_ws_kernel(double* ws) {
    if (threadIdx.x < 4) ws[threadIdx.x] = 0.0;
}

__global__ __launch_bounds__(256) void euler_kernel(
    const float* __restrict__ Field,
    const float* __restrict__ W,
    const float* __restrict__ bvec,
    const float* __restrict__ thermal,
    float* __restrict__ out,
    double* __restrict__ ws)
{
    __shared__ float sW[180];
    __shared__ float sB[16];
    __shared__ float sRed[4][4];

    const int t = threadIdx.x;
    if (t < 180) sW[t] = W[t];
    if (t < 15)  sB[t] = bvec[t];
    const float th = thermal[0];
    __syncthreads();

    const int tid = blockIdx.x * 256 + t;
    const int x  = tid % IX;
    const int ry = tid / IX;
    const int y  = ry % IY;
    const int b  = ry / IY;

    // circular wraps
    const int xm1 = (x == 0)      ? IX - 1       : x - 1;
    const int xm2 = (x < 2)       ? x + IX - 2   : x - 2;
    const int xp1 = (x == IX - 1) ? 0            : x + 1;
    const int xp2 = (x >= IX - 2) ? x - (IX - 2) : x + 2;
    const int ym1 = (y == 0)      ? IY - 1       : y - 1;
    const int ym2 = (y < 2)       ? y + IY - 2   : y - 2;
    const int yp1 = (y == IY - 1) ? 0            : y + 1;
    const int yp2 = (y >= IY - 2) ? y - (IY - 2) : y + 2;

    const float* base = Field + (size_t)b * NCH * PLANE;

    float ctr[12], fdx[12], fdy[12];
#pragma unroll
    for (int c = 0; c < 12; ++c) {
        const float* row = base + c * PLANE + y * IX;
        const float a0 = row[xm2], a1 = row[xm1], a2 = row[x];
        const float a3 = row[xp1], a4 = row[xp2];
        ctr[c] = a2;
        fdx[c] = (a0 - a4 + 8.0f * (a3 - a1)) * (1.0f / 12.0f);
        const float* col = base + c * PLANE + x;
        const float b0 = col[ym2 * IX], b1 = col[ym1 * IX];
        const float b3 = col[yp1 * IX], b4 = col[yp2 * IX];
        fdy[c] = (b0 - b4 + 8.0f * (b3 - b1)) * (1.0f / 12.0f);
    }

    // ml[o] = sum_c W[o,c] * Field[c] + bias[o]
    float ml[15];
#pragma unroll
    for (int o = 0; o < 15; ++o) {
        float acc = sB[o];
#pragma unroll
        for (int c = 0; c < 12; ++c) acc = fmaf(sW[o * 12 + c], ctr[c], acc);
        ml[o] = acc;
    }

    float c2 = 0.f, ef2 = 0.f, pp2 = 0.f, xy2 = 0.f;
    float* ob = out + (size_t)b * NCH * PLANE + y * IX + x;

#pragma unroll
    for (int z = 0; z < 3; ++z) {
        const int zp = (z == 2) ? 0 : z + 1;
        const int zm = (z == 0) ? 2 : z - 1;
        const float uz = ctr[z], vz = ctr[3 + z], Tz = ctr[6 + z];
        const float oz = ml[12 + z];
        const float invp = (z == 0) ? 0.1f : (z == 1) ? (1.0f / 8.5f) : 0.2f;
#pragma unroll
        for (int f = 0; f < 4; ++f) {
            const int c = f * 3 + z;
            const float fdz = 0.5f * (ctr[f * 3 + zp] - ctr[f * 3 + zm]);
            const float xyd = -uz * fdx[c] - vz * fdy[c];
            float ph;
            if      (f == 0) ph = -fdx[9 + z];
            else if (f == 1) ph = -fdy[9 + z];
            else if (f == 2) ph = th * Tz * invp * oz;
            else             ph = 0.0f;
            const float physics = xyd - oz * fdz + ph;
            ob[c * PLANE] = ctr[c] + ml[c] + physics;  // Field_new
            ef2 = fmaf(ml[c],   ml[c],   ef2);
            pp2 = fmaf(physics, physics, pp2);
            xy2 = fmaf(xyd,     xyd,     xy2);
        }
        const float dzo = 0.5f * (ml[12 + zp] - ml[12 + zm]);
        const float con = fdx[z] + fdy[3 + z] + dzo;
        c2 = fmaf(con, con, c2);
    }

    // block reduction of the 4 partial sums
    float vals[4] = { c2, ef2, pp2, xy2 };
    const int lane = t & 63;
    const int wv   = t >> 6;
#pragma unroll
    for (int i = 0; i < 4; ++i) {
        float v = vals[i];
        for (int off = 32; off > 0; off >>= 1) v += __shfl_down(v, off, 64);
        if (lane == 0) sRed[wv][i] = v;
    }
    __syncthreads();
    if (t < 4) {
        const double s = (double)sRed[0][t] + (double)sRed[1][t]
                       + (double)sRed[2][t] + (double)sRed[3][t];
        atomicAdd(&ws[t], s);
    }
}

__global__ void finalize_kernel(const double* __restrict__ ws, float* __restrict__ out) {
    if (threadIdx.x == 0) {
        out[NOUT + 0] = (float)(ws[0] / (double)(NB * 3 * PLANE));  // mean(constrain^2)
        out[NOUT + 1] = (float)(ws[1] / (double)NOUT);              // mean(ExternalForce^2)
        out[NOUT + 2] = (float)(ws[2] / (double)NOUT);              // mean(PhysicsPart^2)
        out[NOUT + 3] = (float)(ws[3] / (double)NOUT);              // mean(xydirection^2)
    }
}

extern "C" void kernel_launch(void* const* d_in, const int* in_sizes, int n_in,
                              void* d_out, int out_size, void* d_ws, size_t ws_size,
                              hipStream_t stream) {
    const float* Field   = (const float*)d_in[0];
    const float* W       = (const float*)d_in[1];
    const float* bvec    = (const float*)d_in[2];
    const float* thermal = (const float*)d_in[3];
    float*  out = (float*)d_out;
    double* ws  = (double*)d_ws;

    zero_ws_kernel<<<1, 64, 0, stream>>>(ws);
    euler_kernel<<<(NB * PLANE) / 256, 256, 0, stream>>>(Field, W, bvec, thermal, out, ws);
    finalize_kernel<<<1, 64, 0, stream>>>(ws, out);
}

// Round 2
// 138.203 us; speedup vs baseline: 1.7975x; 1.7975x over previous
//
#include <hip/hip_runtime.h>

#define IX 1440
#define IY 720
#define NB 4
#define NCH 12
#define PLANE (IY * IX)            // 1,036,800
#define NOUT (NB * NCH * PLANE)    // 49,766,400
#define NTHREADS (NB * PLANE / 4)  // 1,036,800 threads, 4 px each
#define NWG (NTHREADS / 256)       // 4050
#define SWZ_Q (NWG / 8)            // 506
#define SWZ_R (NWG % 8)            // 2

__global__ void zero_ws_kernel(double* ws) {
    if (threadIdx.x < 4) ws[threadIdx.x] = 0.0;
}

__device__ __forceinline__ void ld4(const float* p, float o[4]) {
    const float4 v = *reinterpret_cast<const float4*>(p);
    o[0] = v.x; o[1] = v.y; o[2] = v.z; o[3] = v.w;
}

__global__ __launch_bounds__(256) void euler_kernel(
    const float* __restrict__ Field,
    const float* __restrict__ W,
    const float* __restrict__ bvec,
    const float* __restrict__ thermal,
    float* __restrict__ out,
    double* __restrict__ ws)
{
    __shared__ float sW[180];
    __shared__ float sB[16];
    __shared__ float sRed[4][4];

    const int t = threadIdx.x;
    if (t < 180) sW[t] = W[t];
    if (t < 15)  sB[t] = bvec[t];
    const float th = thermal[0];
    __syncthreads();

    // bijective XCD-slab swizzle (m204): xcd = bid%8 owns a contiguous work chunk
    const int bid = blockIdx.x;
    const int xcd = bid & 7, pos = bid >> 3;
    const int wg  = (xcd < SWZ_R ? xcd * (SWZ_Q + 1)
                                 : SWZ_R * (SWZ_Q + 1) + (xcd - SWZ_R) * SWZ_Q) + pos;

    const int tid = wg * 256 + t;
    const int xi  = tid % 360;          // which float4 in the row
    const int row = tid / 360;          // global (b,y) row
    const int x4  = xi * 4;
    const int y   = row % IY;
    const int b   = row / IY;

    // circular wraps (float4-aligned in x)
    const int xm  = (x4 == 0)      ? IX - 4 : x4 - 4;
    const int xp  = (x4 == IX - 4) ? 0      : x4 + 4;
    const int ym1 = (y == 0)      ? IY - 1       : y - 1;
    const int ym2 = (y < 2)       ? y + IY - 2   : y - 2;
    const int yp1 = (y == IY - 1) ? 0            : y + 1;
    const int yp2 = (y >= IY - 2) ? y - (IY - 2) : y + 2;

    const float* base = Field + (size_t)b * NCH * PLANE;
    const size_t ro = (size_t)y * IX;

    // center values, all 12 channels (needed by matvec + z-derivs)
    float ctr[12][4];
#pragma unroll
    for (int c = 0; c < 12; ++c) ld4(base + (size_t)c * PLANE + ro + x4, ctr[c]);

    // ml[12..14] (the "o" channels) — needed by every physics term
    float ml12[3][4];
#pragma unroll
    for (int z = 0; z < 3; ++z) {
#pragma unroll
        for (int j = 0; j < 4; ++j) ml12[z][j] = sB[12 + z];
#pragma unroll
        for (int cc = 0; cc < 12; ++cc) {
            const float wv = sW[(12 + z) * 12 + cc];
#pragma unroll
            for (int j = 0; j < 4; ++j) ml12[z][j] = fmaf(wv, ctr[cc][j], ml12[z][j]);
        }
    }

    // constrain accumulator: start with dz(o)
    float con[3][4];
#pragma unroll
    for (int z = 0; z < 3; ++z) {
        const int zp = (z == 2) ? 0 : z + 1;
        const int zm = (z == 0) ? 2 : z - 1;
#pragma unroll
        for (int j = 0; j < 4; ++j) con[z][j] = 0.5f * (ml12[zp][j] - ml12[zm][j]);
    }

    float fdx9[3][4], fdy9[3][4];
    float c2 = 0.f, ef2 = 0.f, pp2 = 0.f, xy2 = 0.f;
    float* ob = out + (size_t)b * NCH * PLANE + ro + x4;

    // channels in order 9,10,11 (f=3) first, then 0..8 — so fdx9/fdy9 are ready
#pragma unroll
    for (int ci = 0; ci < 12; ++ci) {
        const int c = (ci < 3) ? 9 + ci : ci - 3;
        const int f = c / 3, z = c % 3;
        const int zp = (z == 2) ? 0 : z + 1;
        const int zm = (z == 0) ? 2 : z - 1;
        const float invp = (z == 0) ? 0.1f : (z == 1) ? (1.0f / 8.5f) : 0.2f;
        const float* pc = base + (size_t)c * PLANE;

        float vxm[4], vxp[4], vm2[4], vm1[4], vp1[4], vp2[4];
        ld4(pc + ro + xm, vxm);
        ld4(pc + ro + xp, vxp);
        ld4(pc + (size_t)ym2 * IX + x4, vm2);
        ld4(pc + (size_t)ym1 * IX + x4, vm1);
        ld4(pc + (size_t)yp1 * IX + x4, vp1);
        ld4(pc + (size_t)yp2 * IX + x4, vp2);

        // 12-wide x window: [xm(4) | ctr(4) | xp(4)], pixel j sits at w[4+j]
        float w[12];
#pragma unroll
        for (int j = 0; j < 4; ++j) { w[j] = vxm[j]; w[4 + j] = ctr[c][j]; w[8 + j] = vxp[j]; }

        float fdx[4], fdy[4];
#pragma unroll
        for (int j = 0; j < 4; ++j) {
            fdx[j] = (w[2 + j] - w[6 + j] + 8.0f * (w[5 + j] - w[3 + j])) * (1.0f / 12.0f);
            fdy[j] = (vm2[j] - vp2[j] + 8.0f * (vp1[j] - vm1[j])) * (1.0f / 12.0f);
        }

        // per-channel matvec output
        float mlc[4];
#pragma unroll
        for (int j = 0; j < 4; ++j) mlc[j] = sB[c];
#pragma unroll
        for (int cc = 0; cc < 12; ++cc) {
            const float wv = sW[c * 12 + cc];
#pragma unroll
            for (int j = 0; j < 4; ++j) mlc[j] = fmaf(wv, ctr[cc][j], mlc[j]);
        }

        if (f == 3) {
#pragma unroll
            for (int j = 0; j < 4; ++j) { fdx9[z][j] = fdx[j]; fdy9[z][j] = fdy[j]; }
        }
        if (f == 0) {
#pragma unroll
            for (int j = 0; j < 4; ++j) con[z][j] += fdx[j];
        }
        if (f == 1) {
#pragma unroll
            for (int j = 0; j < 4; ++j) con[z][j] += fdy[j];
        }

        float st[4];
#pragma unroll
        for (int j = 0; j < 4; ++j) {
            const float fdz = 0.5f * (ctr[f * 3 + zp][j] - ctr[f * 3 + zm][j]);
            const float xyd = -ctr[z][j] * fdx[j] - ctr[3 + z][j] * fdy[j];
            float ph;
            if      (f == 0) ph = -fdx9[z][j];
            else if (f == 1) ph = -fdy9[z][j];
            else if (f == 2) ph = th * ctr[6 + z][j] * invp * ml12[z][j];
            else             ph = 0.0f;
            const float phys = xyd - ml12[z][j] * fdz + ph;
            st[j] = ctr[c][j] + mlc[j] + phys;
            ef2 = fmaf(mlc[j],  mlc[j],  ef2);
            pp2 = fmaf(phys,    phys,    pp2);
            xy2 = fmaf(xyd,     xyd,     xy2);
        }
        *reinterpret_cast<float4*>(ob + (size_t)c * PLANE) =
            make_float4(st[0], st[1], st[2], st[3]);
    }

#pragma unroll
    for (int z = 0; z < 3; ++z)
#pragma unroll
        for (int j = 0; j < 4; ++j) c2 = fmaf(con[z][j], con[z][j], c2);

    // block reduction of the 4 partial sums
    float vals[4] = { c2, ef2, pp2, xy2 };
    const int lane = t & 63;
    const int wv   = t >> 6;
#pragma unroll
    for (int i = 0; i < 4; ++i) {
        float v = vals[i];
        for (int off = 32; off > 0; off >>= 1) v += __shfl_down(v, off, 64);
        if (lane == 0) sRed[wv][i] = v;
    }
    __syncthreads();
    if (t < 4) {
        const double s = (double)sRed[0][t] + (double)sRed[1][t]
                       + (double)sRed[2][t] + (double)sRed[3][t];
        atomicAdd(&ws[t], s);
    }
}

__global__ void finalize_kernel(const double* __restrict__ ws, float* __restrict__ out) {
    if (threadIdx.x == 0) {
        out[NOUT + 0] = (float)(ws[0] / (double)(NB * 3 * PLANE));  // mean(constrain^2)
        out[NOUT + 1] = (float)(ws[1] / (double)NOUT);              // mean(ExternalForce^2)
        out[NOUT + 2] = (float)(ws[2] / (double)NOUT);              // mean(PhysicsPart^2)
        out[NOUT + 3] = (float)(ws[3] / (double)NOUT);              // mean(xydirection^2)
    }
}

extern "C" void kernel_launch(void* const* d_in, const int* in_sizes, int n_in,
                              void* d_out, int out_size, void* d_ws, size_t ws_size,
                              hipStream_t stream) {
    const float* Field   = (const float*)d_in[0];
    const float* W       = (const float*)d_in[1];
    const float* bvec    = (const float*)d_in[2];
    const float* thermal = (const float*)d_in[3];
    float*  out = (float*)d_out;
    double* ws  = (double*)d_ws;

    zero_ws_kernel<<<1, 64, 0, stream>>>(ws);
    euler_kernel<<<NWG, 256, 0, stream>>>(Field, W, bvec, thermal, out, ws);
    finalize_kernel<<<1, 64, 0, stream>>>(ws, out);
}

// Round 4
// 127.905 us; speedup vs baseline: 1.9422x; 1.0805x over previous
//
#include <hip/hip_runtime.h>

#define IX 1440
#define IY 720
#define NB 4
#define NCH 12
#define PLANE (IY * IX)            // 1,036,800
#define NOUT (NB * NCH * PLANE)    // 49,766,400
#define NTHREADS (NB * PLANE / 4)  // 1,036,800 threads, 4 px each
#define NWG (NTHREADS / 256)       // 4050
#define SWZ_Q (NWG / 8)            // 506
#define SWZ_R (NWG % 8)            // 2

typedef float f4v __attribute__((ext_vector_type(4)));

__global__ void zero_ws_kernel(double* ws) {
    if (threadIdx.x < 4) ws[threadIdx.x] = 0.0;
}

__device__ __forceinline__ void ld4(const float* p, float o[4]) {
    const f4v v = *reinterpret_cast<const f4v*>(p);
    o[0] = v.x; o[1] = v.y; o[2] = v.z; o[3] = v.w;
}

__global__ __launch_bounds__(256) void euler_kernel(
    const float* __restrict__ Field,
    const float* __restrict__ W,
    const float* __restrict__ bvec,
    const float* __restrict__ thermal,
    float* __restrict__ out,
    double* __restrict__ ws)
{
    __shared__ float sW[180];
    __shared__ float sB[16];
    __shared__ float sRed[4][4];

    const int t = threadIdx.x;
    if (t < 180) sW[t] = W[t];
    if (t < 15)  sB[t] = bvec[t];
    const float th = thermal[0];
    __syncthreads();

    // bijective XCD-slab swizzle (m204)
    const int bid = blockIdx.x;
    const int xcd = bid & 7, pos = bid >> 3;
    const int wg  = (xcd < SWZ_R ? xcd * (SWZ_Q + 1)
                                 : SWZ_R * (SWZ_Q + 1) + (xcd - SWZ_R) * SWZ_Q) + pos;

    const int tid = wg * 256 + t;
    const int xi  = tid % 360;
    const int row = tid / 360;
    const int x4  = xi * 4;
    const int y   = row % IY;
    const int b   = row / IY;

    const int xm  = (x4 == 0)      ? IX - 4 : x4 - 4;
    const int xp  = (x4 == IX - 4) ? 0      : x4 + 4;
    const int ym1 = (y == 0)      ? IY - 1       : y - 1;
    const int ym2 = (y < 2)       ? y + IY - 2   : y - 2;
    const int yp1 = (y == IY - 1) ? 0            : y + 1;
    const int yp2 = (y >= IY - 2) ? y - (IY - 2) : y + 2;

    const float* base = Field + (size_t)b * NCH * PLANE;
    const size_t ro = (size_t)y * IX;

    // center values, all 12 channels (batched independent loads)
    float ctr[12][4];
#pragma unroll
    for (int c = 0; c < 12; ++c) ld4(base + (size_t)c * PLANE + ro + x4, ctr[c]);

    // ml[12..14] ("o") — needed by every physics term
    float ml12[3][4];
#pragma unroll
    for (int z = 0; z < 3; ++z) {
#pragma unroll
        for (int j = 0; j < 4; ++j) ml12[z][j] = sB[12 + z];
#pragma unroll
        for (int cc = 0; cc < 12; ++cc) {
            const float wv = sW[(12 + z) * 12 + cc];
#pragma unroll
            for (int j = 0; j < 4; ++j) ml12[z][j] = fmaf(wv, ctr[cc][j], ml12[z][j]);
        }
    }

    float c2 = 0.f, ef2 = 0.f, pp2 = 0.f, xy2 = 0.f;
    float* ob = out + (size_t)b * NCH * PLANE + ro + x4;

    // z-group order: per z process f = 3, 0, 1, 2  →  fdx9/fdy9/con are transient
#pragma unroll
    for (int z = 0; z < 3; ++z) {
        const int zp = (z == 2) ? 0 : z + 1;
        const int zm = (z == 0) ? 2 : z - 1;
        const float invp = (z == 0) ? 0.1f : (z == 1) ? (1.0f / 8.5f) : 0.2f;

        float fdx9[4], fdy9[4];
        float conz[4];
#pragma unroll
        for (int j = 0; j < 4; ++j) conz[j] = 0.5f * (ml12[zp][j] - ml12[zm][j]);

#pragma unroll
        for (int fi = 0; fi < 4; ++fi) {
            const int f = (fi == 0) ? 3 : fi - 1;   // 3,0,1,2
            const int c = f * 3 + z;
            const float* pc = base + (size_t)c * PLANE;

            float vxm[4], vxp[4], vm2[4], vm1[4], vp1[4], vp2[4];
            ld4(pc + ro + xm, vxm);
            ld4(pc + ro + xp, vxp);
            ld4(pc + (size_t)ym2 * IX + x4, vm2);
            ld4(pc + (size_t)ym1 * IX + x4, vm1);
            ld4(pc + (size_t)yp1 * IX + x4, vp1);
            ld4(pc + (size_t)yp2 * IX + x4, vp2);

            float w[12];
#pragma unroll
            for (int j = 0; j < 4; ++j) { w[j] = vxm[j]; w[4 + j] = ctr[c][j]; w[8 + j] = vxp[j]; }

            float fdx[4], fdy[4];
#pragma unroll
            for (int j = 0; j < 4; ++j) {
                fdx[j] = (w[2 + j] - w[6 + j] + 8.0f * (w[5 + j] - w[3 + j])) * (1.0f / 12.0f);
                fdy[j] = (vm2[j] - vp2[j] + 8.0f * (vp1[j] - vm1[j])) * (1.0f / 12.0f);
            }

            float mlc[4];
#pragma unroll
            for (int j = 0; j < 4; ++j) mlc[j] = sB[c];
#pragma unroll
            for (int cc = 0; cc < 12; ++cc) {
                const float wv = sW[c * 12 + cc];
#pragma unroll
                for (int j = 0; j < 4; ++j) mlc[j] = fmaf(wv, ctr[cc][j], mlc[j]);
            }

            if (f == 3) {
#pragma unroll
                for (int j = 0; j < 4; ++j) { fdx9[j] = fdx[j]; fdy9[j] = fdy[j]; }
            }
            if (f == 0) {
#pragma unroll
                for (int j = 0; j < 4; ++j) conz[j] += fdx[j];
            }
            if (f == 1) {
#pragma unroll
                for (int j = 0; j < 4; ++j) conz[j] += fdy[j];
            }

            float st[4];
#pragma unroll
            for (int j = 0; j < 4; ++j) {
                const float fdz = 0.5f * (ctr[f * 3 + zp][j] - ctr[f * 3 + zm][j]);
                const float xyd = -ctr[z][j] * fdx[j] - ctr[3 + z][j] * fdy[j];
                float ph;
                if      (f == 0) ph = -fdx9[j];
                else if (f == 1) ph = -fdy9[j];
                else if (f == 2) ph = th * ctr[6 + z][j] * invp * ml12[z][j];
                else             ph = 0.0f;
                const float phys = xyd - ml12[z][j] * fdz + ph;
                st[j] = ctr[c][j] + mlc[j] + phys;
                ef2 = fmaf(mlc[j],  mlc[j],  ef2);
                pp2 = fmaf(phys,    phys,    pp2);
                xy2 = fmaf(xyd,     xyd,     xy2);
            }
            // output is never re-read: keep it out of L2 so the read window fits
            f4v sv; sv.x = st[0]; sv.y = st[1]; sv.z = st[2]; sv.w = st[3];
            __builtin_nontemporal_store(sv, reinterpret_cast<f4v*>(ob + (size_t)c * PLANE));
        }

#pragma unroll
        for (int j = 0; j < 4; ++j) c2 = fmaf(conz[j], conz[j], c2);
    }

    // block reduction of the 4 partial sums
    float vals[4] = { c2, ef2, pp2, xy2 };
    const int lane = t & 63;
    const int wv   = t >> 6;
#pragma unroll
    for (int i = 0; i < 4; ++i) {
        float v = vals[i];
        for (int off = 32; off > 0; off >>= 1) v += __shfl_down(v, off, 64);
        if (lane == 0) sRed[wv][i] = v;
    }
    __syncthreads();
    if (t < 4) {
        const double s = (double)sRed[0][t] + (double)sRed[1][t]
                       + (double)sRed[2][t] + (double)sRed[3][t];
        atomicAdd(&ws[t], s);
    }
}

__global__ void finalize_kernel(const double* __restrict__ ws, float* __restrict__ out) {
    if (threadIdx.x == 0) {
        out[NOUT + 0] = (float)(ws[0] / (double)(NB * 3 * PLANE));
        out[NOUT + 1] = (float)(ws[1] / (double)NOUT);
        out[NOUT + 2] = (float)(ws[2] / (double)NOUT);
        out[NOUT + 3] = (float)(ws[3] / (double)NOUT);
    }
}

extern "C" void kernel_launch(void* const* d_in, const int* in_sizes, int n_in,
                              void* d_out, int out_size, void* d_ws, size_t ws_size,
                              hipStream_t stream) {
    const float* Field   = (const float*)d_in[0];
    const float* W       = (const float*)d_in[1];
    const float* bvec    = (const float*)d_in[2];
    const float* thermal = (const float*)d_in[3];
    float*  out = (float*)d_out;
    double* ws  = (double*)d_ws;

    zero_ws_kernel<<<1, 64, 0, stream>>>(ws);
    euler_kernel<<<NWG, 256, 0, stream>>>(Field, W, bvec, thermal, out, ws);
    finalize_kernel<<<1, 64, 0, stream>>>(ws, out);
}